// Round 16
// baseline (437.396 us; speedup 1.0000x reference)
//
#include <hip/hip_runtime.h>
#include <float.h>

#define NN 20000
#define EE 160000
#define GG 64
#define DD 512
#define NL 3
#define M2 40000
#define M2P 40960   // 160 panels of 256 (panels % 8 == 0 for XCD swizzle)
#define M1 20000
#define M1P 20480   // 80 panels of 256
#define BK 64

typedef __bf16 bf16x8 __attribute__((ext_vector_type(8)));
typedef float f32x4 __attribute__((ext_vector_type(4)));
typedef unsigned int u32;
typedef unsigned short u16;
typedef u32 u32x4 __attribute__((ext_vector_type(4)));
typedef u32 u32x2 __attribute__((ext_vector_type(2)));

union FragU { u32x4 u; bf16x8 b; };

__device__ inline float blo(u32 u){ union{u32 i;float f;}x; x.i=u<<16; return x.f; }
__device__ inline float bhi(u32 u){ union{u32 i;float f;}x; x.i=u&0xFFFF0000u; return x.f; }
__device__ inline u16 f2bf(float f){ union{float f;u32 i;}x; x.f=f; u32 r=x.i+0x7FFFu+((x.i>>16)&1u); return (u16)(r>>16); }
__device__ inline u32 pack2(float a,float b){ return (u32)f2bf(a) | ((u32)f2bf(b)<<16); }

__device__ __forceinline__ void gload16(const void* g, void* lds){
  __builtin_amdgcn_global_load_lds(
    (const __attribute__((address_space(1))) void*)g,
    (__attribute__((address_space(3))) void*)lds, 16, 0, 0);
}

__device__ __forceinline__ void acc8(float* a, uint4 q, float w){
  a[0]+=w*blo(q.x); a[1]+=w*bhi(q.x);
  a[2]+=w*blo(q.y); a[3]+=w*bhi(q.y);
  a[4]+=w*blo(q.z); a[5]+=w*bhi(q.z);
  a[6]+=w*blo(q.w); a[7]+=w*bhi(q.w);
}

// ---------------- merged: fp32->bf16 convert (padded) + degree histogram ----------------
__global__ void k_cvtdeg(const float* __restrict__ in, u16* __restrict__ outp,
                         const int* __restrict__ ei, int* __restrict__ deg){
  int b = blockIdx.x;
  if(b < 12800){
    int t = b*256+threadIdx.x;           // t < M1P*160 exactly
    int row = t/160, gidx = t%160;
    u32x4 o;
    if(row < M1){
      const float* s = in + (size_t)row*1280 + gidx*8;
      float4 v0 = *(const float4*)s;
      float4 v1 = *(const float4*)(s+4);
      o.x=pack2(v0.x,v0.y); o.y=pack2(v0.z,v0.w);
      o.z=pack2(v1.x,v1.y); o.w=pack2(v1.z,v1.w);
    } else {
      o.x=o.y=o.z=o.w=0u;
    }
    *(u32x4*)(outp + (size_t)row*1280 + gidx*8) = o;
  } else {
    int e = (b-12800)*256+threadIdx.x;
    if(e<EE) atomicAdd(&deg[ei[EE+e]], 1);
  }
}

// ---------------- transpose helpers (device) ----------------
__device__ __forceinline__ void dev_tcvt(const float* __restrict__ in, u16* __restrict__ outp,
                                         int R, int C, int bx, int by, int tx, int ty, float* t){
  int c0 = bx*32, r0 = by*32;
  t[ty*33+tx] = in[(size_t)(r0+ty)*C + c0+tx];
  __syncthreads();
  outp[(size_t)(c0+ty)*R + r0+tx] = f2bf(t[tx*33+ty]);
}
__device__ __forceinline__ void dev_t32(const float* __restrict__ in, float* __restrict__ outp,
                                        int R, int C, int bx, int by, int tx, int ty, float* t){
  int c0 = bx*32, r0 = by*32;
  int r = r0+ty, c = c0+tx;
  if(r<R && c<C) t[ty*33+tx] = in[(size_t)r*C + c];
  __syncthreads();
  int oc = c0+ty, orr = r0+tx;
  if(oc<C && orr<R) outp[(size_t)oc*R + orr] = t[tx*33+ty];
}

// ---------------- merged prep: all weight transposes + embp, block-range dispatch ----------------
__global__ __launch_bounds__(1024) void k_prep(const float* __restrict__ pesm_w, u16* __restrict__ WtE,
    const float* __restrict__ gcn_w, u16* __restrict__ WtG,
    const float* __restrict__ ro1_w, float* __restrict__ roT1,
    const float* __restrict__ ro2_w, float* __restrict__ roT2,
    const float* __restrict__ et, const float* __restrict__ paa_w,
    const float* __restrict__ paa_b, float* __restrict__ embp){
  __shared__ float t[32*33];
  int rb = blockIdx.x;
  int tid = threadIdx.x;
  int tx = tid&31, ty = tid>>5;
  if(rb < 640){ dev_tcvt(pesm_w, WtE, 1280, 512, rb%16, rb/16, tx, ty, t); return; }
  rb -= 640;
  if(rb < 768){
    int z = rb/256, r2 = rb%256;
    dev_tcvt(gcn_w + (size_t)z*262144, WtG + (size_t)z*262144, 512, 512, r2%16, r2/16, tx, ty, t);
    return;
  }
  rb -= 768;
  if(rb < 512){ dev_t32(ro1_w, roT1, 512, 1024, rb%32, rb/32, tx, ty, t); return; }
  rb -= 512;
  if(rb < 512){ dev_t32(ro2_w, roT2, 1024, 500, rb%16, rb/16, tx, ty, t); return; }
  rb -= 512;
  {
    int tt = rb*1024 + tid;
    if(tt < 21*512){
      int a = tt>>9, d = tt&511;
      float s = paa_b[d];
      for(int k=0;k<96;k++) s += et[a*96+k]*paa_w[k*512+d];
      embp[tt] = s;
    }
  }
}

// ---------------- parallel scan: A (block-local prefix + dis + bounds), B (block sums), C (add base) ----
__global__ __launch_bounds__(1024) void k_scanA(const int* __restrict__ deg, int* __restrict__ loff,
                        float* __restrict__ dis, const int* __restrict__ batch,
                        int* __restrict__ starts, int* __restrict__ bsum){
  __shared__ int ws[16];
  int b = blockIdx.x, tid = threadIdx.x;
  int n = b*1024 + tid;
  int lane = tid & 63, wv = tid >> 6;
  int dv = 0;
  if(n < NN){ dv = deg[n]; dis[n] = rsqrtf((float)dv + 1.0f); }
  int v = dv;
  #pragma unroll
  for(int off=1; off<64; off<<=1){
    int t = __shfl_up(v, off, 64);
    if(lane >= off) v += t;
  }
  if(lane==63) ws[wv] = v;
  __syncthreads();
  if(wv==0){
    int s = (lane<16)? ws[lane] : 0;
    #pragma unroll
    for(int off=1; off<16; off<<=1){
      int t = __shfl_up(s, off, 64);
      if(lane>=off) s += t;
    }
    if(lane<16) ws[lane] = s;
  }
  __syncthreads();
  int wbase = wv ? ws[wv-1] : 0;
  if(n < NN) loff[n] = wbase + v - dv;     // exclusive prefix within block
  if(tid==1023) bsum[b] = ws[15];          // block total
  if(n < NN){
    int bb = batch[n];
    int pb = n ? batch[n-1] : -1;
    for(int g=pb+1; g<=bb; g++) starts[g]=n;
    if(n==NN-1){ for(int g=bb+1; g<=GG; g++) starts[g]=NN; }
  }
}
__global__ void k_scanB(const int* __restrict__ bsum, int* __restrict__ bbase){
  int lane = threadIdx.x;
  int x = (lane<20)? bsum[lane] : 0;
  int v = x;
  #pragma unroll
  for(int off=1; off<32; off<<=1){
    int t = __shfl_up(v, off, 64);
    if(lane>=off) v += t;
  }
  if(lane<20) bbase[lane] = v - x;         // exclusive
}
__global__ void k_scanC(const int* __restrict__ loff, const int* __restrict__ bbase,
                        int* __restrict__ offs){
  int n = blockIdx.x*1024 + threadIdx.x;
  if(n < NN) offs[n] = bbase[n>>10] + loff[n];
  if(n == 0) offs[NN] = EE;
}
__global__ void k_fill(const int* __restrict__ ei, const int* __restrict__ offs, int* __restrict__ curs,
                       const float* __restrict__ dis, int2* __restrict__ edat){
  int e = blockIdx.x*256+threadIdx.x; if(e>=EE) return;
  int s = ei[e], d = ei[EE+e];
  int pos = atomicAdd(&curs[d],1);
  edat[offs[d]+pos] = make_int2(s*2048, __float_as_int(dis[s]*dis[d]));
}

// ============ 8-phase counted-vmcnt MFMA GEMM: BM=256,BN=256,BK=64, 8 waves ============
// Grid: 2*(M/256) blocks. Decode: xr=w&7 (XCD), kk2=w>>3, n0=(kk2&1)*256, panel=(xr+8*(kk2>>1))*256.
// LDS: 2 dbuf x {A,B} x 2 K-halves of [256 rows][32 cols] = 8 x 16KB = 128KB.
// Per K-tile: 4 phases {dsread; stage 1 half; [vmcnt(4)]; barrier; lgkmcnt0; 16 MFMA; barrier}.
// Counted vmcnt keeps 4 prefetch loads in flight across barriers (never drains in main loop).
#define ASM_VMCNT4 asm volatile("s_waitcnt vmcnt(4)" ::: "memory")
#define ASM_VMCNT0 asm volatile("s_waitcnt vmcnt(0)" ::: "memory")
#define ASM_LGKM0  asm volatile("s_waitcnt lgkmcnt(0)" ::: "memory")

template<int EPI>
__global__ __launch_bounds__(512,2) void k_gemm8(const u16* __restrict__ A, const u16* __restrict__ Bt,
                                              u16* __restrict__ C, int Mstore, int K, int lda,
                                              const int* __restrict__ nx, const float* __restrict__ embp,
                                              const float* __restrict__ esm_b){
  __shared__ u16 ls[8*8192];    // [buf][mat][kh] panels of 256x32
  const int tid = threadIdx.x;
  const int lane = tid & 63;
  const int wid = tid >> 6;        // 0..7
  const int wr = wid >> 2;         // 0..1 -> 128-row band
  const int wc = wid & 3;          // 0..3 -> 64-col band
  const int la = lane & 15, lg = lane >> 4;
  const int w = blockIdx.x;
  const int xr = w & 7, kk2 = w >> 3;
  const int n0 = (kk2 & 1) * 256;
  const int rowB = (xr + 8*(kk2 >> 1)) * 256;
  const int nt = K >> 6;

  const u16* Arow = A + (size_t)rowB*lda;
  const u16* Brow = Bt + (size_t)n0*K;

  f32x4 acc[8][4];
  #pragma unroll
  for(int m=0;m<8;m++)
    #pragma unroll
    for(int n=0;n<4;n++)
      #pragma unroll
      for(int r=0;r<4;r++) acc[m][n][r]=0.f;

  // staging decode: slot s=j*512+tid -> row=s>>2, cp=s&3; source chunk = cp^((row>>1)&3)
  int srow[2], sgc[2];
  #pragma unroll
  for(int j=0;j<2;j++){
    int s = j*512+tid;
    srow[j] = s>>2;
    sgc[j]  = ((s&3) ^ ((srow[j]>>1)&3))*8;
  }

#define PANEL(buf,mat,kh) (ls + (((buf)*2+(mat))*2+(kh))*8192)
#define STAGE(buf,mat,kh,kt) { \
    const u16* _src = (mat)? Brow : Arow; \
    int _ld = (mat)? K : lda; \
    int _k0 = (kt)*64 + (kh)*32; \
    u16* _dst = PANEL(buf,mat,kh); \
    _Pragma("unroll") \
    for(int _j=0;_j<2;_j++) \
      gload16(_src + (size_t)srow[_j]*_ld + _k0 + sgc[_j], _dst + (_j*512+tid)*8); \
  }
#define LDA4(f,buf,kh,qm) { \
    const u16* _pa = PANEL(buf,0,kh); \
    _Pragma("unroll") \
    for(int _m=0;_m<4;_m++){ \
      int _row = wr*128 + (qm)*64 + _m*16 + la; \
      f[_m].u = *(const u32x4*)(_pa + _row*32 + ((lg ^ ((_row>>1)&3))*8)); \
    } \
  }
#define LDB4(f,buf,kh) { \
    const u16* _pb = PANEL(buf,1,kh); \
    _Pragma("unroll") \
    for(int _n=0;_n<4;_n++){ \
      int _row = wc*64 + _n*16 + la; \
      f[_n].u = *(const u32x4*)(_pb + _row*32 + ((lg ^ ((_row>>1)&3))*8)); \
    } \
  }
#define MM16(af,bf,qm) { \
    _Pragma("unroll") \
    for(int _m=0;_m<4;_m++) \
      _Pragma("unroll") \
      for(int _n=0;_n<4;_n++) \
        acc[(qm)*4+_m][_n] = __builtin_amdgcn_mfma_f32_16x16x32_bf16(af[_m].b, bf[_n].b, acc[(qm)*4+_m][_n], 0,0,0); \
  }

  // prologue: stage tile0 in order [Ak0, Bk0, Ak1, Bk1] into buf0
  STAGE(0,0,0,0); STAGE(0,1,0,0); STAGE(0,0,1,0); STAGE(0,1,1,0);
  ASM_VMCNT4;                     // Ak0,Bk0 landed (Ak1,Bk1 = 4 loads still in flight)
  __builtin_amdgcn_s_barrier();

  for(int t=0;t<nt;t++){
    const int c = t&1;
    const bool st = (t+1 < nt);
    const bool lastt = (t == nt-1);
    FragU aF[4], b0F[4], b1F[4];

    // ---- phase 1: kk0/qm0 reads + B(kk0); stage t+1.Ak0
    LDA4(aF, c, 0, 0); LDB4(b0F, c, 0);
    if(st) STAGE(c^1, 0, 0, t+1);
    __builtin_amdgcn_s_barrier();
    ASM_LGKM0; __builtin_amdgcn_sched_barrier(0);
    __builtin_amdgcn_s_setprio(1); MM16(aF, b0F, 0); __builtin_amdgcn_s_setprio(0);
    __builtin_amdgcn_s_barrier();

    // ---- phase 2: kk0/qm1; stage t+1.Bk0; wait protects phase-3 reads (t.Ak1,t.Bk1)
    LDA4(aF, c, 0, 1);
    if(st) STAGE(c^1, 1, 0, t+1);
    if(lastt){ ASM_VMCNT0; } else { ASM_VMCNT4; }
    __builtin_amdgcn_s_barrier();
    ASM_LGKM0; __builtin_amdgcn_sched_barrier(0);
    __builtin_amdgcn_s_setprio(1); MM16(aF, b0F, 1); __builtin_amdgcn_s_setprio(0);
    __builtin_amdgcn_s_barrier();

    // ---- phase 3: kk1/qm0 + B(kk1); stage t+1.Ak1
    LDA4(aF, c, 1, 0); LDB4(b1F, c, 1);
    if(st) STAGE(c^1, 0, 1, t+1);
    __builtin_amdgcn_s_barrier();
    ASM_LGKM0; __builtin_amdgcn_sched_barrier(0);
    __builtin_amdgcn_s_setprio(1); MM16(aF, b1F, 0); __builtin_amdgcn_s_setprio(0);
    __builtin_amdgcn_s_barrier();

    // ---- phase 4: kk1/qm1; stage t+1.Bk1; wait protects next tile's phase-1 reads
    LDA4(aF, c, 1, 1);
    if(st) STAGE(c^1, 1, 1, t+1);
    if(!lastt){ ASM_VMCNT4; }
    __builtin_amdgcn_s_barrier();
    ASM_LGKM0; __builtin_amdgcn_sched_barrier(0);
    __builtin_amdgcn_s_setprio(1); MM16(aF, b1F, 1); __builtin_amdgcn_s_setprio(0);
    __builtin_amdgcn_s_barrier();
  }

  // epilogue: per-wave C = 128x64 at (rowB + wr*128, n0 + wc*64)
  #pragma unroll
  for(int m=0;m<8;m++)
    #pragma unroll
    for(int r=0;r<4;r++){
      int rr = rowB + wr*128 + m*16 + lg*4 + r;
      if(rr < Mstore){
        int aidx = (EPI==1) ? nx[rr] : 0;
        #pragma unroll
        for(int n=0;n<4;n++){
          int col = n0 + wc*64 + n*16 + la;
          float v = acc[m][n][r];
          if(EPI==0){
            C[(size_t)rr*512 + col] = f2bf(v);
          } else {
            float t1 = v + esm_b[col];
            float hh = embp[aidx*512 + col] + t1;
            C[(size_t)(2*rr)*512 + col]   = f2bf(hh>0.f?hh:0.f);
            C[(size_t)(2*rr+1)*512 + col] = f2bf(t1>0.f?t1:0.f);
          }
        }
      }
    }
#undef PANEL
#undef STAGE
#undef LDA4
#undef LDB4
#undef MM16
}

// ---------------- stack-split agg, 4 waves/block, single-pass 2x-unrolled ----------
template<int MODE>
__global__ __launch_bounds__(256) void k_agg7(const u16* __restrict__ hW, u16* __restrict__ feat,
                 const int* __restrict__ offs, const int2* __restrict__ edat,
                 const float* __restrict__ dis, const float* __restrict__ bias){
  const int b = blockIdx.x;
  const int sl = b & 1;
  const int wv = threadIdx.x >> 6;
  const int lane = threadIdx.x & 63;
  const int nn = (b>>1)*4 + wv;
  const int co = sl*1024 + lane*16;    // byte offset within 2KB row-pair
  const char* base = (const char*)hW;
  const int e0 = offs[nn], e1 = offs[nn+1];
  float a[8]={0,0,0,0,0,0,0,0};

  uint4 qs = *(const uint4*)(base + (size_t)nn*2048 + co);
  uint4 qf = make_uint4(0,0,0,0);
  if(MODE>0) qf = *(const uint4*)((const char*)feat + (size_t)nn*2048 + co);
  float dn = dis[nn], sn = dn*dn;

  int e = e0;
  for(; e+1 < e1; e += 2){
    int2 edA = edat[e], edB = edat[e+1];
    uint4 qA = *(const uint4*)(base + (u32)edA.x + co);
    uint4 qB = *(const uint4*)(base + (u32)edB.x + co);
    acc8(a, qA, __int_as_float(edA.y));
    acc8(a, qB, __int_as_float(edB.y));
  }
  if(e < e1){
    int2 edA = edat[e];
    uint4 qA = *(const uint4*)(base + (u32)edA.x + co);
    acc8(a, qA, __int_as_float(edA.y));
  }
  acc8(a, qs, sn);

  float4 b0 = *(const float4*)(bias + lane*8);
  float4 b1 = *(const float4*)(bias + lane*8 + 4);
  a[0]+=b0.x; a[1]+=b0.y; a[2]+=b0.z; a[3]+=b0.w;
  a[4]+=b1.x; a[5]+=b1.y; a[6]+=b1.z; a[7]+=b1.w;
  #pragma unroll
  for(int j=0;j<8;j++) a[j] = a[j]>0.f ? a[j] : 0.f;
  if(MODE>0) acc8(a, qf, 1.f);
  uint4 o;
  o.x=pack2(a[0],a[1]); o.y=pack2(a[2],a[3]);
  o.z=pack2(a[4],a[5]); o.w=pack2(a[6],a[7]);
  *(uint4*)((char*)feat + (size_t)nn*2048 + co) = o;
}

// ---------------- partial max pool (values >= 0), interleaved contiguous pairs ----------------
__global__ void k_pool(const u16* __restrict__ feat, const int* __restrict__ starts,
                       u32* __restrict__ m1, u32* __restrict__ m3){
  int g = blockIdx.x, c = blockIdx.y;
  int s = starts[g], e = starts[g+1];
  int len = e - s;
  int b0 = s + (len*c)/8, b1 = s + (len*(c+1))/8;
  int t = threadIdx.x;
  float a0=0.f, a1=0.f, c0=0.f, c1=0.f;
  for(int n=b0;n<b1;++n){
    const u16* pr = feat + (size_t)(2*n)*512 + t*2;
    u32 q1 = *(const u32*)pr;
    u32 q3 = *(const u32*)(pr + 512);
    a0 = fmaxf(a0, blo(q1)); a1 = fmaxf(a1, bhi(q1));
    c0 = fmaxf(c0, blo(q3)); c1 = fmaxf(c1, bhi(q3));
  }
  atomicMax(m1 + g*512 + t*2,     __float_as_uint(a0));
  atomicMax(m1 + g*512 + t*2 + 1, __float_as_uint(a1));
  atomicMax(m3 + g*512 + t*2,     __float_as_uint(c0));
  atomicMax(m3 + g*512 + t*2 + 1, __float_as_uint(c1));
}

// ---------------- readout 1 with fused gcomb: wave-per-output dot products ----------------
__global__ __launch_bounds__(256) void k_ro1v(const u32* __restrict__ m1b, const u32* __restrict__ m3b,
                                              const float* __restrict__ w1, const float* __restrict__ wT,
                                              const float* __restrict__ b, float* __restrict__ r1){
  int gw = blockIdx.x*4 + (threadIdx.x>>6);   // 0..65535  (g*1024+o)
  int g = gw >> 10, o = gw & 1023;
  int lane = threadIdx.x & 63;
  float w10 = w1[0], w11 = w1[1];
  const uint4* g1 = (const uint4*)(m1b + (size_t)g*512);
  const uint4* g3 = (const uint4*)(m3b + (size_t)g*512);
  const float4* wr = (const float4*)(wT + (size_t)o*512);
  float s = 0.f;
  #pragma unroll
  for(int i=0;i<2;i++){
    uint4 q1 = g1[i*64+lane];
    uint4 q3 = g3[i*64+lane];
    float4 w = wr[i*64+lane];
    s += (w10*__uint_as_float(q1.x) + w11*__uint_as_float(q3.x))*w.x;
    s += (w10*__uint_as_float(q1.y) + w11*__uint_as_float(q3.y))*w.y;
    s += (w10*__uint_as_float(q1.z) + w11*__uint_as_float(q3.z))*w.z;
    s += (w10*__uint_as_float(q1.w) + w11*__uint_as_float(q3.w))*w.w;
  }
  #pragma unroll
  for(int m=32;m>=1;m>>=1) s += __shfl_xor(s, m, 64);
  if(lane==0){ s += b[o]; r1[gw] = s>0.f ? s : 0.f; }
}
__global__ __launch_bounds__(256) void k_ro2v(const float* __restrict__ r1, const float* __restrict__ wT,
                                              const float* __restrict__ b, float* __restrict__ y){
  int gw = blockIdx.x*4 + (threadIdx.x>>6);   // 0..31999  (g*500+o)
  int g = gw/500, o = gw - g*500;
  int lane = threadIdx.x & 63;
  const float4* gr = (const float4*)(r1 + (size_t)g*1024);
  const float4* wr = (const float4*)(wT + (size_t)o*1024);
  float s = 0.f;
  #pragma unroll
  for(int i=0;i<4;i++){
    float4 a = gr[i*64+lane];
    float4 w = wr[i*64+lane];
    s += a.x*w.x + a.y*w.y + a.z*w.z + a.w*w.w;
  }
  #pragma unroll
  for(int m=32;m>=1;m>>=1) s += __shfl_xor(s, m, 64);
  if(lane==0) y[gw] = 1.0f/(1.0f+__expf(-(s + b[o])));
}

extern "C" void kernel_launch(void* const* d_in, const int* in_sizes, int n_in,
                              void* d_out, int out_size, void* d_ws, size_t ws_size,
                              hipStream_t stream){
  const int*   native_x = (const int*)d_in[0];
  const float* x        = (const float*)d_in[1];
  const int*   ei       = (const int*)d_in[2];
  const int*   batch    = (const int*)d_in[3];
  const float* embed_t  = (const float*)d_in[4];
  const float* paa_w    = (const float*)d_in[5];
  const float* paa_b    = (const float*)d_in[6];
  const float* pesm_w   = (const float*)d_in[7];
  const float* pesm_b   = (const float*)d_in[8];
  const float* gcn_w    = (const float*)d_in[9];
  const float* gcn_b    = (const float*)d_in[10];
  const float* ro1_w    = (const float*)d_in[11];
  const float* ro1_b    = (const float*)d_in[12];
  const float* ro2_w    = (const float*)d_in[13];
  const float* ro2_b    = (const float*)d_in[14];
  const float* w1       = (const float*)d_in[15];
  float* out = (float*)d_out;

  char* p = (char*)d_ws;
  auto alloc = [&](size_t n){ void* r = (void*)p; p += (n + 255) & ~(size_t)255; return r; };
  u16* feat   = (u16*)alloc((size_t)M2P*512*2);
  u16* hW     = (u16*)alloc((size_t)M2P*512*2);
  u16* xbf    = (u16*)alloc((size_t)M1P*1280*2);
  u16* WtE    = (u16*)alloc((size_t)512*1280*2);
  u16* WtG    = (u16*)alloc((size_t)3*512*512*2);
  float* roT1 = (float*)alloc((size_t)1024*512*4);
  float* roT2 = (float*)alloc((size_t)500*1024*4);
  float* embp = (float*)alloc(21*512*4);
  int* deg    = (int*)alloc(NN*4);      // deg, curs back-to-back (one memset covers both)
  int* curs   = (int*)alloc(NN*4);
  float* dis  = (float*)alloc(NN*4);
  int* loff   = (int*)alloc(NN*4);
  int* offs   = (int*)alloc((NN+1)*4);
  int* bsum   = (int*)alloc(32*4);
  int* bbase  = (int*)alloc(32*4);
  int2* edat  = (int2*)alloc((size_t)EE*8);
  int* starts = (int*)alloc((GG+1)*4);
  u32* m1b    = (u32*)alloc(GG*512*4);   // m1b, m3b contiguous
  u32* m3b    = (u32*)alloc(GG*512*4);
  float* r1   = (float*)alloc(GG*1024*4);
  (void)ws_size; (void)in_sizes; (void)n_in; (void)out_size;

  hipMemsetAsync(deg, 0, ((NN*4+255)&~(size_t)255) + NN*4, stream);  // deg + curs
  hipMemsetAsync(m1b, 0, 2*GG*512*4, stream);

  k_cvtdeg<<<12800+625,256,0,stream>>>(x, xbf, ei, deg);
  k_prep<<<640+768+512+512+11,1024,0,stream>>>(pesm_w, WtE, gcn_w, WtG, ro1_w, roT1, ro2_w, roT2,
                                               embed_t, paa_w, paa_b, embp);
  k_scanA<<<20,1024,0,stream>>>(deg, loff, dis, batch, starts, bsum);
  k_scanB<<<1,64,0,stream>>>(bsum, bbase);
  k_scanC<<<20,1024,0,stream>>>(loff, bbase, offs);
  k_fill<<<(EE+255)/256,256,0,stream>>>(ei, offs, curs, dis, edat);

  // x @ proj_esm_w with fused embed/bias/relu epilogue -> feat (interleaved rows 2n/2n+1)
  k_gemm8<1><<<2*(M1P/256),512,0,stream>>>(xbf, WtE, feat, M1, 1280, 1280, native_x, embp, pesm_b);

  // layer 0
  k_gemm8<0><<<2*(M2P/256),512,0,stream>>>(feat, WtG,            hW, M2, 512, 512, nullptr, nullptr, nullptr);
  k_agg7<0><<<NN/2,256,0,stream>>>(hW, feat, offs, edat, dis, gcn_b);
  // layer 1
  k_gemm8<0><<<2*(M2P/256),512,0,stream>>>(feat, WtG+262144,     hW, M2, 512, 512, nullptr, nullptr, nullptr);
  k_agg7<1><<<NN/2,256,0,stream>>>(hW, feat, offs, edat, dis, gcn_b+512);
  // layer 2
  k_gemm8<0><<<2*(M2P/256),512,0,stream>>>(feat, WtG+2*262144,   hW, M2, 512, 512, nullptr, nullptr, nullptr);
  k_agg7<1><<<NN/2,256,0,stream>>>(hW, feat, offs, edat, dis, gcn_b+1024);

  k_pool<<<dim3(GG,8),256,0,stream>>>(feat, starts, m1b, m3b);
  k_ro1v<<<16384,256,0,stream>>>(m1b, m3b, w1, roT1, ro1_b, r1);
  k_ro2v<<<8000,256,0,stream>>>(r1, roT2, ro2_b, out);
}

// Round 17
// 397.569 us; speedup vs baseline: 1.1002x; 1.1002x over previous
//
#include <hip/hip_runtime.h>
#include <float.h>

#define NN 20000
#define EE 160000
#define GG 64
#define DD 512
#define NL 3
#define M2 40000
#define M2P 40960   // 320*128 panels (multiple of 1024 rows for XCD swizzle)
#define M1 20000
#define M1P 20480   // 160*128
#define BK 64

typedef __bf16 bf16x8 __attribute__((ext_vector_type(8)));
typedef float f32x4 __attribute__((ext_vector_type(4)));
typedef unsigned int u32;
typedef unsigned short u16;
typedef u32 u32x4 __attribute__((ext_vector_type(4)));
typedef u32 u32x2 __attribute__((ext_vector_type(2)));

union FragU { u32x4 u; bf16x8 b; };

__device__ inline float blo(u32 u){ union{u32 i;float f;}x; x.i=u<<16; return x.f; }
__device__ inline float bhi(u32 u){ union{u32 i;float f;}x; x.i=u&0xFFFF0000u; return x.f; }
__device__ inline u16 f2bf(float f){ union{float f;u32 i;}x; x.f=f; u32 r=x.i+0x7FFFu+((x.i>>16)&1u); return (u16)(r>>16); }
__device__ inline u32 pack2(float a,float b){ return (u32)f2bf(a) | ((u32)f2bf(b)<<16); }

__device__ __forceinline__ void gload16(const void* g, void* lds){
  __builtin_amdgcn_global_load_lds(
    (const __attribute__((address_space(1))) void*)g,
    (__attribute__((address_space(3))) void*)lds, 16, 0, 0);
}

__device__ __forceinline__ void acc8(float* a, uint4 q, float w){
  a[0]+=w*blo(q.x); a[1]+=w*bhi(q.x);
  a[2]+=w*blo(q.y); a[3]+=w*bhi(q.y);
  a[4]+=w*blo(q.z); a[5]+=w*bhi(q.z);
  a[6]+=w*blo(q.w); a[7]+=w*bhi(q.w);
}

// ---------------- merged: fp32->bf16 convert (padded) + degree histogram ----------------
__global__ void k_cvtdeg(const float* __restrict__ in, u16* __restrict__ outp,
                         const int* __restrict__ ei, int* __restrict__ deg){
  int b = blockIdx.x;
  if(b < 12800){
    int t = b*256+threadIdx.x;           // t < M1P*160 exactly
    int row = t/160, gidx = t%160;
    u32x4 o;
    if(row < M1){
      const float* s = in + (size_t)row*1280 + gidx*8;
      float4 v0 = *(const float4*)s;
      float4 v1 = *(const float4*)(s+4);
      o.x=pack2(v0.x,v0.y); o.y=pack2(v0.z,v0.w);
      o.z=pack2(v1.x,v1.y); o.w=pack2(v1.z,v1.w);
    } else {
      o.x=o.y=o.z=o.w=0u;
    }
    *(u32x4*)(outp + (size_t)row*1280 + gidx*8) = o;
  } else {
    int e = (b-12800)*256+threadIdx.x;
    if(e<EE) atomicAdd(&deg[ei[EE+e]], 1);
  }
}

// ---------------- transpose helpers (device) ----------------
__device__ __forceinline__ void dev_tcvt(const float* __restrict__ in, u16* __restrict__ outp,
                                         int R, int C, int bx, int by, int tx, int ty, float* t){
  int c0 = bx*32, r0 = by*32;
  t[ty*33+tx] = in[(size_t)(r0+ty)*C + c0+tx];
  __syncthreads();
  outp[(size_t)(c0+ty)*R + r0+tx] = f2bf(t[tx*33+ty]);
}
__device__ __forceinline__ void dev_t32(const float* __restrict__ in, float* __restrict__ outp,
                                        int R, int C, int bx, int by, int tx, int ty, float* t){
  int c0 = bx*32, r0 = by*32;
  int r = r0+ty, c = c0+tx;
  if(r<R && c<C) t[ty*33+tx] = in[(size_t)r*C + c];
  __syncthreads();
  int oc = c0+ty, orr = r0+tx;
  if(oc<C && orr<R) outp[(size_t)oc*R + orr] = t[tx*33+ty];
}

// ---------------- merged prep: all weight transposes + embp, block-range dispatch ----------------
__global__ __launch_bounds__(1024) void k_prep(const float* __restrict__ pesm_w, u16* __restrict__ WtE,
    const float* __restrict__ gcn_w, u16* __restrict__ WtG,
    const float* __restrict__ ro1_w, float* __restrict__ roT1,
    const float* __restrict__ ro2_w, float* __restrict__ roT2,
    const float* __restrict__ et, const float* __restrict__ paa_w,
    const float* __restrict__ paa_b, float* __restrict__ embp){
  __shared__ float t[32*33];
  int rb = blockIdx.x;
  int tid = threadIdx.x;
  int tx = tid&31, ty = tid>>5;
  if(rb < 640){ dev_tcvt(pesm_w, WtE, 1280, 512, rb%16, rb/16, tx, ty, t); return; }
  rb -= 640;
  if(rb < 768){
    int z = rb/256, r2 = rb%256;
    dev_tcvt(gcn_w + (size_t)z*262144, WtG + (size_t)z*262144, 512, 512, r2%16, r2/16, tx, ty, t);
    return;
  }
  rb -= 768;
  if(rb < 512){ dev_t32(ro1_w, roT1, 512, 1024, rb%32, rb/32, tx, ty, t); return; }
  rb -= 512;
  if(rb < 512){ dev_t32(ro2_w, roT2, 1024, 500, rb%16, rb/16, tx, ty, t); return; }
  rb -= 512;
  {
    int tt = rb*1024 + tid;
    if(tt < 21*512){
      int a = tt>>9, d = tt&511;
      float s = paa_b[d];
      for(int k=0;k<96;k++) s += et[a*96+k]*paa_w[k*512+d];
      embp[tt] = s;
    }
  }
}

// ---------------- parallel scan: A (block-local prefix + dis + bounds), C (scan bsum + add base) ----
__global__ __launch_bounds__(1024) void k_scanA(const int* __restrict__ deg, int* __restrict__ loff,
                        float* __restrict__ dis, const int* __restrict__ batch,
                        int* __restrict__ starts, int* __restrict__ bsum){
  __shared__ int ws[16];
  int b = blockIdx.x, tid = threadIdx.x;
  int n = b*1024 + tid;
  int lane = tid & 63, wv = tid >> 6;
  int dv = 0;
  if(n < NN){ dv = deg[n]; dis[n] = rsqrtf((float)dv + 1.0f); }
  int v = dv;
  #pragma unroll
  for(int off=1; off<64; off<<=1){
    int t = __shfl_up(v, off, 64);
    if(lane >= off) v += t;
  }
  if(lane==63) ws[wv] = v;
  __syncthreads();
  if(wv==0){
    int s = (lane<16)? ws[lane] : 0;
    #pragma unroll
    for(int off=1; off<16; off<<=1){
      int t = __shfl_up(s, off, 64);
      if(lane>=off) s += t;
    }
    if(lane<16) ws[lane] = s;
  }
  __syncthreads();
  int wbase = wv ? ws[wv-1] : 0;
  if(n < NN) loff[n] = wbase + v - dv;     // exclusive prefix within block
  if(tid==1023) bsum[b] = ws[15];          // block total
  if(n < NN){
    int bb = batch[n];
    int pb = n ? batch[n-1] : -1;
    for(int g=pb+1; g<=bb; g++) starts[g]=n;
    if(n==NN-1){ for(int g=bb+1; g<=GG; g++) starts[g]=NN; }
  }
}
__global__ __launch_bounds__(1024) void k_scanC(const int* __restrict__ loff, const int* __restrict__ bsum,
                        int* __restrict__ offs){
  int b = blockIdx.x;
  int base = 0;
  #pragma unroll 4
  for(int i=0;i<b;i++) base += bsum[i];    // 20-entry scan, redundant per block (trivial)
  int n = b*1024 + threadIdx.x;
  if(n < NN) offs[n] = base + loff[n];
  if(n == 0) offs[NN] = EE;
}
__global__ void k_fill(const int* __restrict__ ei, const int* __restrict__ offs, int* __restrict__ curs,
                       const float* __restrict__ dis, int2* __restrict__ edat){
  int e = blockIdx.x*256+threadIdx.x; if(e>=EE) return;
  int s = ei[e], d = ei[EE+e];
  int pos = atomicAdd(&curs[d],1);
  edat[offs[d]+pos] = make_int2(s*2048, __float_as_int(dis[s]*dis[d]));
}

// ---------------- MFMA GEMM (m97 structure + XCD-cooperative swizzle, 128x128) ----------------
// 1D grid of 4*npan blocks (npan%8==0). Decode: r=w&7, k=w>>3, x=k&3, y=r+8*(k>>2).
template<int EPI>
__global__ __launch_bounds__(256) void k_gemm(const u16* __restrict__ A, const u16* __restrict__ Bt,
                                              u16* __restrict__ C, int Mstore, int K, int lda,
                                              const int* __restrict__ nx, const float* __restrict__ embp,
                                              const float* __restrict__ esm_b){
  __shared__ u16 lsA[128*BK];
  __shared__ u16 lsB[128*BK];
  const int tid = threadIdx.x;
  const int lane = tid & 63;
  const int wid = tid >> 6;
  const int wr = wid >> 1, wc = wid & 1;
  const int la = lane & 15, lg = lane >> 4;
  const int w = blockIdx.x;
  const int xr = w & 7, kk2 = w >> 3;
  const int n0 = (kk2 & 3) * 128;
  const int rowB = (xr + 8*(kk2 >> 2)) * 128;

  f32x4 acc[4][4];
  #pragma unroll
  for(int m=0;m<4;m++)
    #pragma unroll
    for(int n=0;n<4;n++)
      #pragma unroll
      for(int r=0;r<4;r++) acc[m][n][r]=0.f;

  const u16* Arow = A + (size_t)rowB*lda;
  const u16* Brow = Bt + (size_t)n0*K;

  int srow[4], scol[4], ldsoff[4];
  #pragma unroll
  for(int i=0;i<4;i++){
    int li = i*256+tid;
    srow[i] = li>>3;
    scol[i] = ((li&7) ^ (srow[i]&7))*8;
    ldsoff[i] = (i*256 + wid*64)*8;
  }

  for(int k0=0;k0<K;k0+=BK){
    #pragma unroll
    for(int i=0;i<4;i++)
      gload16(Arow + (size_t)srow[i]*lda + k0 + scol[i], lsA + ldsoff[i]);
    #pragma unroll
    for(int i=0;i<4;i++)
      gload16(Brow + (size_t)srow[i]*K + k0 + scol[i], lsB + ldsoff[i]);
    __syncthreads();
    #pragma unroll
    for(int kk=0;kk<2;kk++){
      FragU aF[4], bF[4];
      #pragma unroll
      for(int m=0;m<4;m++){
        int row = wr*64+m*16+la;
        aF[m].u = *(const u32x4*)&lsA[row*BK + ((kk*4+lg)^(row&7))*8];
      }
      #pragma unroll
      for(int n=0;n<4;n++){
        int row = wc*64+n*16+la;
        bF[n].u = *(const u32x4*)&lsB[row*BK + ((kk*4+lg)^(row&7))*8];
      }
      #pragma unroll
      for(int m=0;m<4;m++)
        #pragma unroll
        for(int n=0;n<4;n++)
          acc[m][n] = __builtin_amdgcn_mfma_f32_16x16x32_bf16(aF[m].b, bF[n].b, acc[m][n], 0,0,0);
    }
    __syncthreads();
  }
  #pragma unroll
  for(int m=0;m<4;m++)
    #pragma unroll
    for(int r=0;r<4;r++){
      int rr = rowB + wr*64 + m*16 + lg*4 + r;
      if(rr < Mstore){
        int aidx = (EPI==1) ? nx[rr] : 0;
        #pragma unroll
        for(int n=0;n<4;n++){
          int col = n0 + wc*64 + n*16 + la;
          float v = acc[m][n][r];
          if(EPI==0){
            C[(size_t)rr*512 + col] = f2bf(v);
          } else {
            float t1 = v + esm_b[col];
            float hh = embp[aidx*512 + col] + t1;
            C[(size_t)(2*rr)*512 + col]   = f2bf(hh>0.f?hh:0.f);
            C[(size_t)(2*rr+1)*512 + col] = f2bf(t1>0.f?t1:0.f);
          }
        }
      }
    }
}

// ---------------- stack-split agg, 4 waves/block, single-pass 2x-unrolled ----------
template<int MODE>
__global__ __launch_bounds__(256) void k_agg7(const u16* __restrict__ hW, u16* __restrict__ feat,
                 const int* __restrict__ offs, const int2* __restrict__ edat,
                 const float* __restrict__ dis, const float* __restrict__ bias){
  const int b = blockIdx.x;
  const int sl = b & 1;
  const int wv = threadIdx.x >> 6;
  const int lane = threadIdx.x & 63;
  const int nn = (b>>1)*4 + wv;
  const int co = sl*1024 + lane*16;    // byte offset within 2KB row-pair
  const char* base = (const char*)hW;
  const int e0 = offs[nn], e1 = offs[nn+1];
  float a[8]={0,0,0,0,0,0,0,0};

  uint4 qs = *(const uint4*)(base + (size_t)nn*2048 + co);
  uint4 qf = make_uint4(0,0,0,0);
  if(MODE>0) qf = *(const uint4*)((const char*)feat + (size_t)nn*2048 + co);
  float dn = dis[nn], sn = dn*dn;

  int e = e0;
  for(; e+1 < e1; e += 2){
    int2 edA = edat[e], edB = edat[e+1];
    uint4 qA = *(const uint4*)(base + (u32)edA.x + co);
    uint4 qB = *(const uint4*)(base + (u32)edB.x + co);
    acc8(a, qA, __int_as_float(edA.y));
    acc8(a, qB, __int_as_float(edB.y));
  }
  if(e < e1){
    int2 edA = edat[e];
    uint4 qA = *(const uint4*)(base + (u32)edA.x + co);
    acc8(a, qA, __int_as_float(edA.y));
  }
  acc8(a, qs, sn);

  float4 b0 = *(const float4*)(bias + lane*8);
  float4 b1 = *(const float4*)(bias + lane*8 + 4);
  a[0]+=b0.x; a[1]+=b0.y; a[2]+=b0.z; a[3]+=b0.w;
  a[4]+=b1.x; a[5]+=b1.y; a[6]+=b1.z; a[7]+=b1.w;
  #pragma unroll
  for(int j=0;j<8;j++) a[j] = a[j]>0.f ? a[j] : 0.f;
  if(MODE>0) acc8(a, qf, 1.f);
  uint4 o;
  o.x=pack2(a[0],a[1]); o.y=pack2(a[2],a[3]);
  o.z=pack2(a[4],a[5]); o.w=pack2(a[6],a[7]);
  *(uint4*)((char*)feat + (size_t)nn*2048 + co) = o;
}

// ---------------- partial max pool (values >= 0), interleaved contiguous pairs ----------------
__global__ void k_pool(const u16* __restrict__ feat, const int* __restrict__ starts,
                       u32* __restrict__ m1, u32* __restrict__ m3){
  int g = blockIdx.x, c = blockIdx.y;
  int s = starts[g], e = starts[g+1];
  int len = e - s;
  int b0 = s + (len*c)/8, b1 = s + (len*(c+1))/8;
  int t = threadIdx.x;
  float a0=0.f, a1=0.f, c0=0.f, c1=0.f;
  for(int n=b0;n<b1;++n){
    const u16* pr = feat + (size_t)(2*n)*512 + t*2;
    u32 q1 = *(const u32*)pr;
    u32 q3 = *(const u32*)(pr + 512);
    a0 = fmaxf(a0, blo(q1)); a1 = fmaxf(a1, bhi(q1));
    c0 = fmaxf(c0, blo(q3)); c1 = fmaxf(c1, bhi(q3));
  }
  atomicMax(m1 + g*512 + t*2,     __float_as_uint(a0));
  atomicMax(m1 + g*512 + t*2 + 1, __float_as_uint(a1));
  atomicMax(m3 + g*512 + t*2,     __float_as_uint(c0));
  atomicMax(m3 + g*512 + t*2 + 1, __float_as_uint(c1));
}

// ---------------- readout 1 with fused gcomb: wave-per-output dot products ----------------
__global__ __launch_bounds__(256) void k_ro1v(const u32* __restrict__ m1b, const u32* __restrict__ m3b,
                                              const float* __restrict__ w1, const float* __restrict__ wT,
                                              const float* __restrict__ b, float* __restrict__ r1){
  int gw = blockIdx.x*4 + (threadIdx.x>>6);   // 0..65535  (g*1024+o)
  int g = gw >> 10, o = gw & 1023;
  int lane = threadIdx.x & 63;
  float w10 = w1[0], w11 = w1[1];
  const uint4* g1 = (const uint4*)(m1b + (size_t)g*512);
  const uint4* g3 = (const uint4*)(m3b + (size_t)g*512);
  const float4* wr = (const float4*)(wT + (size_t)o*512);
  float s = 0.f;
  #pragma unroll
  for(int i=0;i<2;i++){
    uint4 q1 = g1[i*64+lane];
    uint4 q3 = g3[i*64+lane];
    float4 w = wr[i*64+lane];
    s += (w10*__uint_as_float(q1.x) + w11*__uint_as_float(q3.x))*w.x;
    s += (w10*__uint_as_float(q1.y) + w11*__uint_as_float(q3.y))*w.y;
    s += (w10*__uint_as_float(q1.z) + w11*__uint_as_float(q3.z))*w.z;
    s += (w10*__uint_as_float(q1.w) + w11*__uint_as_float(q3.w))*w.w;
  }
  #pragma unroll
  for(int m=32;m>=1;m>>=1) s += __shfl_xor(s, m, 64);
  if(lane==0){ s += b[o]; r1[gw] = s>0.f ? s : 0.f; }
}
__global__ __launch_bounds__(256) void k_ro2v(const float* __restrict__ r1, const float* __restrict__ wT,
                                              const float* __restrict__ b, float* __restrict__ y){
  int gw = blockIdx.x*4 + (threadIdx.x>>6);   // 0..31999  (g*500+o)
  int g = gw/500, o = gw - g*500;
  int lane = threadIdx.x & 63;
  const float4* gr = (const float4*)(r1 + (size_t)g*1024);
  const float4* wr = (const float4*)(wT + (size_t)o*1024);
  float s = 0.f;
  #pragma unroll
  for(int i=0;i<4;i++){
    float4 a = gr[i*64+lane];
    float4 w = wr[i*64+lane];
    s += a.x*w.x + a.y*w.y + a.z*w.z + a.w*w.w;
  }
  #pragma unroll
  for(int m=32;m>=1;m>>=1) s += __shfl_xor(s, m, 64);
  if(lane==0) y[gw] = 1.0f/(1.0f+__expf(-(s + b[o])));
}

extern "C" void kernel_launch(void* const* d_in, const int* in_sizes, int n_in,
                              void* d_out, int out_size, void* d_ws, size_t ws_size,
                              hipStream_t stream){
  const int*   native_x = (const int*)d_in[0];
  const float* x        = (const float*)d_in[1];
  const int*   ei       = (const int*)d_in[2];
  const int*   batch    = (const int*)d_in[3];
  const float* embed_t  = (const float*)d_in[4];
  const float* paa_w    = (const float*)d_in[5];
  const float* paa_b    = (const float*)d_in[6];
  const float* pesm_w   = (const float*)d_in[7];
  const float* pesm_b   = (const float*)d_in[8];
  const float* gcn_w    = (const float*)d_in[9];
  const float* gcn_b    = (const float*)d_in[10];
  const float* ro1_w    = (const float*)d_in[11];
  const float* ro1_b    = (const float*)d_in[12];
  const float* ro2_w    = (const float*)d_in[13];
  const float* ro2_b    = (const float*)d_in[14];
  const float* w1       = (const float*)d_in[15];
  float* out = (float*)d_out;

  char* p = (char*)d_ws;
  auto alloc = [&](size_t n){ void* r = (void*)p; p += (n + 255) & ~(size_t)255; return r; };
  u16* feat   = (u16*)alloc((size_t)M2P*512*2);
  u16* hW     = (u16*)alloc((size_t)M2P*512*2);
  u16* xbf    = (u16*)alloc((size_t)M1P*1280*2);
  u16* WtE    = (u16*)alloc((size_t)512*1280*2);
  u16* WtG    = (u16*)alloc((size_t)3*512*512*2);
  float* roT1 = (float*)alloc((size_t)1024*512*4);
  float* roT2 = (float*)alloc((size_t)500*1024*4);
  float* embp = (float*)alloc(21*512*4);
  int* deg    = (int*)alloc(NN*4);      // deg, curs back-to-back (one memset covers both)
  int* curs   = (int*)alloc(NN*4);
  float* dis  = (float*)alloc(NN*4);
  int* loff   = (int*)alloc(NN*4);
  int* offs   = (int*)alloc((NN+1)*4);
  int* bsum   = (int*)alloc(32*4);
  int2* edat  = (int2*)alloc((size_t)EE*8);
  int* starts = (int*)alloc((GG+1)*4);
  u32* m1b    = (u32*)alloc(GG*512*4);   // m1b, m3b contiguous
  u32* m3b    = (u32*)alloc(GG*512*4);
  float* r1   = (float*)alloc(GG*1024*4);
  (void)ws_size; (void)in_sizes; (void)n_in; (void)out_size;

  hipMemsetAsync(deg, 0, ((NN*4+255)&~(size_t)255) + NN*4, stream);  // deg + curs
  hipMemsetAsync(m1b, 0, 2*GG*512*4, stream);

  k_cvtdeg<<<12800+625,256,0,stream>>>(x, xbf, ei, deg);
  k_prep<<<640+768+512+512+11,1024,0,stream>>>(pesm_w, WtE, gcn_w, WtG, ro1_w, roT1, ro2_w, roT2,
                                               embed_t, paa_w, paa_b, embp);
  k_scanA<<<20,1024,0,stream>>>(deg, loff, dis, batch, starts, bsum);
  k_scanC<<<20,1024,0,stream>>>(loff, bsum, offs);
  k_fill<<<(EE+255)/256,256,0,stream>>>(ei, offs, curs, dis, edat);

  // x @ proj_esm_w with fused embed/bias/relu epilogue -> feat (interleaved rows 2n/2n+1)
  k_gemm<1><<<4*(M1P/128),256,0,stream>>>(xbf, WtE, feat, M1, 1280, 1280, native_x, embp, pesm_b);

  // layer 0
  k_gemm<0><<<4*(M2P/128),256,0,stream>>>(feat, WtG,            hW, M2, 512, 512, nullptr, nullptr, nullptr);
  k_agg7<0><<<NN/2,256,0,stream>>>(hW, feat, offs, edat, dis, gcn_b);
  // layer 1
  k_gemm<0><<<4*(M2P/128),256,0,stream>>>(feat, WtG+262144,     hW, M2, 512, 512, nullptr, nullptr, nullptr);
  k_agg7<1><<<NN/2,256,0,stream>>>(hW, feat, offs, edat, dis, gcn_b+512);
  // layer 2
  k_gemm<0><<<4*(M2P/128),256,0,stream>>>(feat, WtG+2*262144,   hW, M2, 512, 512, nullptr, nullptr, nullptr);
  k_agg7<1><<<NN/2,256,0,stream>>>(hW, feat, offs, edat, dis, gcn_b+1024);

  k_pool<<<dim3(GG,8),256,0,stream>>>(feat, starts, m1b, m3b);
  k_ro1v<<<16384,256,0,stream>>>(m1b, m3b, w1, roT1, ro1_b, r1);
  k_ro2v<<<8000,256,0,stream>>>(r1, roT2, ro2_b, out);
}